// Round 1
// baseline (189.301 us; speedup 1.0000x reference)
//
#include <hip/hip_runtime.h>
#include <hip/hip_bf16.h>
#include <stdint.h>

typedef unsigned short u16;
typedef unsigned int   u32;

#define NB   64
#define NN   4096
#define ND   256
#define NTRI 32896   // 256*257/2

// ---------- helpers ----------
__device__ __forceinline__ u16 f2bf(float f) {
  union { float f; u32 u; } v; v.f = f;
  u32 r = (v.u + 0x7fffu + ((v.u >> 16) & 1u)) >> 16;   // RNE
  return (u16)r;
}

typedef const __attribute__((address_space(1))) u32* gas_ptr;
typedef __attribute__((address_space(3))) u32*       las_ptr;

__device__ __forceinline__ void gload16(const void* g, void* l) {
  __builtin_amdgcn_global_load_lds((gas_ptr)g, (las_ptr)l, 16, 0, 0);
}

typedef __attribute__((ext_vector_type(8))) __bf16 bf16x8;
typedef __attribute__((ext_vector_type(4))) float  f32x4;

// ---------- K1: fp32 -> bf16, transpose to [b][d][n], partial column sums ----
// grid 64*64 blocks, 256 thr. Block = (b, 64-row n-chunk).
__global__ __launch_bounds__(256) void k_tr(const float* __restrict__ in,
                                            u16* __restrict__ xt,
                                            float* __restrict__ part) {
  __shared__ alignas(16) u16 Ls[64 * 256];     // [n_local][d], 32 KB
  int blk = blockIdx.x;
  int b = blk >> 6, c = blk & 63;
  int n0 = c << 6;
  int t = threadIdx.x;
  int dl = t & 63;           // float4 lane along d
  int rr = t >> 6;           // 0..3 (wave id)
  int d0 = dl << 2;

  const float4* in4 = (const float4*)(in + ((size_t)(b * NN + n0)) * ND);
  float sx = 0.f, sy = 0.f, sz = 0.f, sw = 0.f;
#pragma unroll 4
  for (int j = 0; j < 16; ++j) {
    int nl = (j << 2) + rr;                    // wave rr reads row nl (coalesced 1KB)
    float4 v = in4[nl * 64 + dl];
    sx += v.x; sy += v.y; sz += v.z; sw += v.w;
    ushort4 u;
    u.x = f2bf(v.x); u.y = f2bf(v.y); u.z = f2bf(v.z); u.w = f2bf(v.w);
    *(ushort4*)&Ls[nl * 256 + d0] = u;         // ds_write_b64, ~conflict-free
  }
  // partial sums for mean: layout [(b*64+c)*4 + rr][256]
  float4 s4 = make_float4(sx, sy, sz, sw);
  *(float4*)&part[(((size_t)blk << 2) + rr) * 256 + d0] = s4;

  __syncthreads();
  // write-back: thread t owns column d=t -> xt[b][d][n0..n0+63] (128B run)
  int d = t;
  u16* dst = xt + ((size_t)(b * 256 + d)) * NN + n0;
#pragma unroll
  for (int q = 0; q < 8; ++q) {
    u32 w0 = (u32)Ls[(q * 8 + 0) * 256 + d] | ((u32)Ls[(q * 8 + 1) * 256 + d] << 16);
    u32 w1 = (u32)Ls[(q * 8 + 2) * 256 + d] | ((u32)Ls[(q * 8 + 3) * 256 + d] << 16);
    u32 w2 = (u32)Ls[(q * 8 + 4) * 256 + d] | ((u32)Ls[(q * 8 + 5) * 256 + d] << 16);
    u32 w3 = (u32)Ls[(q * 8 + 6) * 256 + d] | ((u32)Ls[(q * 8 + 7) * 256 + d] << 16);
    uint4 w = make_uint4(w0, w1, w2, w3);
    *(uint4*)(dst + q * 8) = w;                // global_store_dwordx4
  }
}

// ---------- K2: reduce partials -> mean[b][d] ----------
__global__ __launch_bounds__(256) void k_mean(const float* __restrict__ part,
                                              float* __restrict__ mean) {
  int b = blockIdx.x, d = threadIdx.x;
  const float* p = part + (size_t)b * 65536 + d;
  float acc = 0.f;
  for (int q = 0; q < 256; ++q) acc += p[q * 256];
  mean[b * 256 + d] = acc * (1.f / 4096.f);
}

// ---------- K3: bf16 MFMA SYRK, 128x128 triu tiles, optional K-split ----------
// grid = 64 * 3 * KSPLIT blocks, 256 thr (4 waves, 2x2, each 64x64 = 4x4 frags)
template <int KSPLIT>
__global__ __launch_bounds__(256) void k_syrk(const u16* __restrict__ xt,
                                              const float* __restrict__ mean,
                                              float* __restrict__ out,
                                              float* __restrict__ covp) {
  int blk = blockIdx.x;
  int s   = blk % KSPLIT;
  int t3  = blk / KSPLIT;          // b*3 + tsel
  int b   = t3 / 3;
  int tsel = t3 % 3;               // 0:(0,0) 1:(0,1) 2:(1,1)
  int ti = (tsel == 2) ? 1 : 0;
  int tj = (tsel == 0) ? 0 : 1;
  bool diag = (ti == tj);

  __shared__ alignas(16) u16 As[128 * 32];   // [row][k], 64B rows -> bank-uniform
  __shared__ alignas(16) u16 Bs[128 * 32];

  int t = threadIdx.x;
  int lane = t & 63;
  int wid = t >> 6;
  int wr = wid >> 1, wc = wid & 1;
  int fr = lane & 15, fg = lane >> 4;

  f32x4 acc[4][4];
  f32x4 zero = {0.f, 0.f, 0.f, 0.f};
#pragma unroll
  for (int m = 0; m < 4; ++m)
#pragma unroll
    for (int n = 0; n < 4; ++n) acc[m][n] = zero;

  const u16* Ab = xt + (size_t)(b * 256 + ti * 128) * NN;
  const u16* Bb = xt + (size_t)(b * 256 + tj * 128) * NN;

  int aoff[4], boff[4];
#pragma unroll
  for (int m = 0; m < 4; ++m) aoff[m] = (wr * 64 + m * 16 + fr) * 32 + fg * 8;
#pragma unroll
  for (int n = 0; n < 4; ++n) boff[n] = (wc * 64 + n * 16 + fr) * 32 + fg * 8;
  const u16* Bsrc = diag ? As : Bs;

  const int KLEN = NN / KSPLIT;
  const int kbeg = s * KLEN;
  const int NSTEP = KLEN / 32;

  int c0 = t, c1 = t + 256;                   // 512 16B chunks per 128x32 tile
  int r0 = c0 >> 2, kc0 = (c0 & 3) << 3;
  int r1 = c1 >> 2, kc1 = (c1 & 3) << 3;

  for (int ks = 0; ks < NSTEP; ++ks) {
    int kb = kbeg + ks * 32;
    __syncthreads();                          // prev-step LDS reads done
    gload16(Ab + (size_t)r0 * NN + kb + kc0, As + c0 * 8);
    gload16(Ab + (size_t)r1 * NN + kb + kc1, As + c1 * 8);
    if (!diag) {
      gload16(Bb + (size_t)r0 * NN + kb + kc0, Bs + c0 * 8);
      gload16(Bb + (size_t)r1 * NN + kb + kc1, Bs + c1 * 8);
    }
    asm volatile("s_waitcnt vmcnt(0)" ::: "memory");
    __syncthreads();

    bf16x8 af[4], bfv[4];
#pragma unroll
    for (int m = 0; m < 4; ++m) af[m] = *(const bf16x8*)(As + aoff[m]);
#pragma unroll
    for (int n = 0; n < 4; ++n) bfv[n] = *(const bf16x8*)(Bsrc + boff[n]);
#pragma unroll
    for (int m = 0; m < 4; ++m)
#pragma unroll
      for (int n = 0; n < 4; ++n)
        acc[m][n] = __builtin_amdgcn_mfma_f32_16x16x32_bf16(af[m], bfv[n], acc[m][n], 0, 0, 0);
  }

  if (KSPLIT == 1) {
    // direct epilogue: /N - mu_i*mu_j, triu pack
    const float* mb = mean + b * 256;
    float* ob = out + (size_t)b * NTRI;
#pragma unroll
    for (int m = 0; m < 4; ++m) {
      int i0 = ti * 128 + wr * 64 + m * 16 + fg * 4;
#pragma unroll
      for (int q = 0; q < 4; ++q) {
        int i = i0 + q;
        float mi = mb[i];
        int ro = i * 256 - ((i * (i - 1)) >> 1) - i;
#pragma unroll
        for (int n = 0; n < 4; ++n) {
          int j = tj * 128 + wc * 64 + n * 16 + fr;
          if (j >= i) ob[ro + j] = acc[m][n][q] * (1.f / 4096.f) - mi * mb[j];
        }
      }
    }
  } else {
    float* cp = covp + ((size_t)(s * 192 + t3) << 14);   // 128*128 partial
#pragma unroll
    for (int m = 0; m < 4; ++m)
#pragma unroll
      for (int q = 0; q < 4; ++q) {
        int li = wr * 64 + m * 16 + fg * 4 + q;
#pragma unroll
        for (int n = 0; n < 4; ++n) {
          int lj = wc * 64 + n * 16 + fr;
          cp[li * 128 + lj] = acc[m][n][q];
        }
      }
  }
}

// ---------- K4: sum K-split partials, apply mean, pack triu ----------
__global__ __launch_bounds__(256) void k_fin(const float* __restrict__ covp,
                                             const float* __restrict__ mean,
                                             float* __restrict__ out) {
  int blk = blockIdx.x;            // b*3 + tsel
  int b = blk / 3, tsel = blk % 3;
  int ti = (tsel == 2) ? 1 : 0;
  int tj = (tsel == 0) ? 0 : 1;
  const float* mb = mean + b * 256;
  float* ob = out + (size_t)b * NTRI;
  for (int e = threadIdx.x; e < 16384; e += 256) {
    int li = e >> 7, lj = e & 127;
    int i = ti * 128 + li, j = tj * 128 + lj;
    if (j < i) continue;
    float ssum = 0.f;
#pragma unroll
    for (int sp = 0; sp < 4; ++sp)
      ssum += covp[((size_t)(sp * 192 + blk) << 14) + e];
    ob[i * 256 - ((i * (i - 1)) >> 1) + j - i] = ssum * (1.f / 4096.f) - mb[i] * mb[j];
  }
}

// ---------- fallback: fp32 vector SYRK, no workspace ----------
// grid 64*10 (4x4 triu 64-tiles), 256 thr
__global__ __launch_bounds__(256) void k_cov_f32(const float* __restrict__ in,
                                                 float* __restrict__ out) {
  int blk = blockIdx.x;
  int b = blk / 10, ts = blk % 10;
  int ti, tj;
  if (ts < 4)      { ti = 0; tj = ts; }
  else if (ts < 7) { ti = 1; tj = ts - 3; }
  else if (ts < 9) { ti = 2; tj = ts - 5; }
  else             { ti = 3; tj = 3; }
  bool diag = (ti == tj);

  __shared__ float Pa[32][68];
  __shared__ float Pb[32][68];
  __shared__ float smA[64], smB[64];
  int t = threadIdx.x;
  if (t < 64) { smA[t] = 0.f; smB[t] = 0.f; }
  float acc[4][4] = {};
  int ri = t >> 4, rj = t & 15;
  const float* base = in + (size_t)b * NN * ND;

  for (int ks = 0; ks < 128; ++ks) {
    int nk = ks * 32;
    __syncthreads();
    for (int cc = t; cc < 512; cc += 256) {
      int r = cc >> 4, c4 = (cc & 15) << 2;
      *(float4*)&Pa[r][c4] = *(const float4*)(base + (size_t)(nk + r) * ND + ti * 64 + c4);
      if (!diag)
        *(float4*)&Pb[r][c4] = *(const float4*)(base + (size_t)(nk + r) * ND + tj * 64 + c4);
    }
    __syncthreads();
    if (t < 64) {
      float s = 0.f;
      for (int r = 0; r < 32; ++r) s += Pa[r][t];
      smA[t] += s;
    } else if (!diag && t < 128) {
      float s = 0.f;
      for (int r = 0; r < 32; ++r) s += Pb[r][t - 64];
      smB[t - 64] += s;
    }
    float(*Pbb)[68] = diag ? Pa : Pb;
    for (int k = 0; k < 32; ++k) {
      float4 a = *(const float4*)&Pa[k][ri << 2];
      float4 v = *(const float4*)&Pbb[k][rj << 2];
      float av[4] = {a.x, a.y, a.z, a.w};
      float bv[4] = {v.x, v.y, v.z, v.w};
#pragma unroll
      for (int e = 0; e < 4; ++e)
#pragma unroll
        for (int f = 0; f < 4; ++f) acc[e][f] += av[e] * bv[f];
    }
  }
  __syncthreads();
  const float inv = 1.f / 4096.f;
  const float* mB = diag ? smA : smB;
#pragma unroll
  for (int e = 0; e < 4; ++e) {
    int i = ti * 64 + (ri << 2) + e;
    float mi = smA[(ri << 2) + e] * inv;
    int ro = i * 256 - ((i * (i - 1)) >> 1) - i;
#pragma unroll
    for (int f = 0; f < 4; ++f) {
      int j = tj * 64 + (rj << 2) + f;
      if (j >= i)
        out[(size_t)b * NTRI + ro + j] = acc[e][f] * inv - mi * mB[(rj << 2) + f] * inv;
    }
  }
}

// ---------- launch ----------
extern "C" void kernel_launch(void* const* d_in, const int* in_sizes, int n_in,
                              void* d_out, int out_size, void* d_ws, size_t ws_size,
                              hipStream_t stream) {
  const float* in = (const float*)d_in[0];
  float* out = (float*)d_out;

  const size_t XT_B   = (size_t)NB * ND * NN * 2;       // 134,217,728
  const size_t PART_B = (size_t)NB * 256 * 256 * 4;     //  16,777,216
  const size_t MEAN_B = (size_t)NB * 256 * 4;           //      65,536
  const size_t COVP_B = (size_t)4 * 192 * 16384 * 4;    //  50,331,648
  const size_t need_basic = XT_B + PART_B + MEAN_B;
  const size_t need_split = need_basic + COVP_B;

  if (ws_size >= need_basic) {
    u16*   xt   = (u16*)d_ws;
    float* part = (float*)((char*)d_ws + XT_B);
    float* mean = (float*)((char*)d_ws + XT_B + PART_B);
    k_tr<<<NB * 64, 256, 0, stream>>>(in, xt, part);
    k_mean<<<NB, 256, 0, stream>>>(part, mean);
    if (ws_size >= need_split) {
      float* covp = (float*)((char*)d_ws + need_basic);
      k_syrk<4><<<NB * 3 * 4, 256, 0, stream>>>(xt, mean, out, covp);
      k_fin<<<NB * 3, 256, 0, stream>>>(covp, mean, out);
    } else {
      k_syrk<1><<<NB * 3, 256, 0, stream>>>(xt, mean, out, nullptr);
    }
  } else {
    k_cov_f32<<<NB * 10, 256, 0, stream>>>(in, out);
  }
}

// Round 3
// 167.635 us; speedup vs baseline: 1.1292x; 1.1292x over previous
//
#include <hip/hip_runtime.h>
#include <hip/hip_bf16.h>
#include <stdint.h>

typedef unsigned short u16;
typedef unsigned int   u32;

#define NB   64
#define NN   4096
#define ND   256
#define NTRI 32896   // 256*257/2

// ---------- helpers ----------
__device__ __forceinline__ u32 cvtpk(float lo, float hi) {
  u32 r;
  asm("v_cvt_pk_bf16_f32 %0, %1, %2" : "=v"(r) : "v"(lo), "v"(hi));
  return r;
}

typedef const __attribute__((address_space(1))) u32* gas_ptr;
typedef __attribute__((address_space(3))) u32*       las_ptr;

__device__ __forceinline__ void gload16(const void* g, void* l) {
  __builtin_amdgcn_global_load_lds((gas_ptr)g, (las_ptr)l, 16, 0, 0);
}

typedef __attribute__((ext_vector_type(8))) __bf16 bf16x8;
typedef __attribute__((ext_vector_type(4))) float  f32x4;

// ---------- K1: fp32 -> bf16, transpose via XOR-swizzled LDS ----------
// xt layout: [b][nc=n/64][d=256][n_local=64] bf16 (block-tiled transpose)
// LDS Lt[d][n]: 128B rows; 16B chunk j stored at chunk j ^ ((d>>2)&7).
// Write phase: lane c4 owns rows d=4*c4+e (so (d>>2)&7 = c4&7 varies per lane).
// grid 64*64 blocks, 256 thr.
__global__ __launch_bounds__(256) void k_tr(const float* __restrict__ in,
                                            u16* __restrict__ xt,
                                            float* __restrict__ part) {
  __shared__ alignas(16) u16 Lt[256 * 64];   // 32 KB
  int blk = blockIdx.x;
  int b = blk >> 6, c = blk & 63;
  int n0 = c << 6;
  int t = threadIdx.x;
  int c4 = t & 63;          // d-quad index: rows d = 4*c4 + e
  int w  = t >> 6;          // wave id 0..3

  const float4* in4 = (const float4*)(in + ((size_t)(b * NN + n0)) * ND);
  float4 ms = make_float4(0.f, 0.f, 0.f, 0.f);
  int swz = (c4 & 7);       // row-only XOR value for this lane's 4 rows

#pragma unroll
  for (int p = 0; p < 2; ++p) {
    int a0 = w * 4 + p * 2;                  // n-quad pair (a0, a0+1), wave-uniform
    // sub-iter 0: n = a0*4 .. a0*4+3
    float4 u0 = in4[(a0 * 4 + 0) * 64 + c4];
    float4 u1 = in4[(a0 * 4 + 1) * 64 + c4];
    float4 u2 = in4[(a0 * 4 + 2) * 64 + c4];
    float4 u3 = in4[(a0 * 4 + 3) * 64 + c4];
    // sub-iter 1: n = a0*4+4 .. a0*4+7
    float4 v0 = in4[(a0 * 4 + 4) * 64 + c4];
    float4 v1 = in4[(a0 * 4 + 5) * 64 + c4];
    float4 v2 = in4[(a0 * 4 + 6) * 64 + c4];
    float4 v3 = in4[(a0 * 4 + 7) * 64 + c4];
    ms.x += u0.x + u1.x + u2.x + u3.x + v0.x + v1.x + v2.x + v3.x;
    ms.y += u0.y + u1.y + u2.y + u3.y + v0.y + v1.y + v2.y + v3.y;
    ms.z += u0.z + u1.z + u2.z + u3.z + v0.z + v1.z + v2.z + v3.z;
    ms.w += u0.w + u1.w + u2.w + u3.w + v0.w + v1.w + v2.w + v3.w;

    int x = a0 >> 1;                          // 16B chunk index = 2w + p
    int ph = (x ^ swz) << 4;                  // swizzled byte offset within row
    {
      uint4 q = make_uint4(cvtpk(u0.x, u1.x), cvtpk(u2.x, u3.x),
                           cvtpk(v0.x, v1.x), cvtpk(v2.x, v3.x));
      *(uint4*)((char*)Lt + (c4 * 4 + 0) * 128 + ph) = q;
    }
    {
      uint4 q = make_uint4(cvtpk(u0.y, u1.y), cvtpk(u2.y, u3.y),
                           cvtpk(v0.y, v1.y), cvtpk(v2.y, v3.y));
      *(uint4*)((char*)Lt + (c4 * 4 + 1) * 128 + ph) = q;
    }
    {
      uint4 q = make_uint4(cvtpk(u0.z, u1.z), cvtpk(u2.z, u3.z),
                           cvtpk(v0.z, v1.z), cvtpk(v2.z, v3.z));
      *(uint4*)((char*)Lt + (c4 * 4 + 2) * 128 + ph) = q;
    }
    {
      uint4 q = make_uint4(cvtpk(u0.w, u1.w), cvtpk(u2.w, u3.w),
                           cvtpk(v0.w, v1.w), cvtpk(v2.w, v3.w));
      *(uint4*)((char*)Lt + (c4 * 4 + 3) * 128 + ph) = q;
    }
  }
  // mean partials: part[(b*64+c)*4 + w][d] = sum over this wave's 16 n-rows
  *(float4*)&part[((size_t)blk * 4 + w) * 256 + c4 * 4] = ms;

  __syncthreads();

  // read-back: thread t -> (d = it*32 + t>>3, 16B n-chunk j = t&7)
  // global stores fully contiguous: wave writes 1KB runs
#pragma unroll
  for (int it = 0; it < 8; ++it) {
    int d = it * 32 + (t >> 3);
    int j = t & 7;
    int off = d * 128 + ((j ^ ((t >> 5) & 7)) << 4);   // (d>>2)&7 == (t>>5)&7
    uint4 val = *(const uint4*)((const char*)Lt + off);
    *(uint4*)(xt + ((size_t)(b * 64 + c) * 256 + d) * 64 + j * 8) = val;
  }
}

// ---------- K2 (fallback path only): reduce partials -> mean[b][d] ----------
__global__ __launch_bounds__(256) void k_mean(const float* __restrict__ part,
                                              float* __restrict__ mean) {
  int b = blockIdx.x, d = threadIdx.x;
  const float* p = part + (size_t)b * 65536 + d;
  float acc = 0.f;
#pragma unroll 8
  for (int q = 0; q < 256; ++q) acc += p[q * 256];
  mean[b * 256 + d] = acc * (1.f / 4096.f);
}

// ---------- K3: bf16 MFMA SYRK, 128x128 triu tiles, 2-phase pipeline ----------
// xt layout: [b][nc][256][64]. grid = 64 * 3 * KSPLIT blocks, 256 thr.
template <int KSPLIT>
__global__ __launch_bounds__(256) void k_syrk(const u16* __restrict__ xt,
                                              const float* __restrict__ mean,
                                              float* __restrict__ out,
                                              float* __restrict__ covp) {
  int blk = blockIdx.x;
  int s   = blk % KSPLIT;
  int t3  = blk / KSPLIT;          // b*3 + tsel
  int b   = t3 / 3;
  int tsel = t3 % 3;               // 0:(0,0) 1:(0,1) 2:(1,1)
  int ti = (tsel == 2) ? 1 : 0;
  int tj = (tsel == 0) ? 0 : 1;
  bool diag = (ti == tj);

  __shared__ alignas(16) u16 As[2][128 * 32];   // double-buffered
  __shared__ alignas(16) u16 Bs[2][128 * 32];

  int t = threadIdx.x;
  int lane = t & 63;
  int wid = t >> 6;
  int wr = wid >> 1, wc = wid & 1;
  int fr = lane & 15, fg = lane >> 4;

  f32x4 acc[4][4];
  f32x4 zero = {0.f, 0.f, 0.f, 0.f};
#pragma unroll
  for (int m = 0; m < 4; ++m)
#pragma unroll
    for (int n = 0; n < 4; ++n) acc[m][n] = zero;

  int dpA = ti * 128, dpB = tj * 128;

  int aoff[4], boff[4];
#pragma unroll
  for (int m = 0; m < 4; ++m) aoff[m] = (wr * 64 + m * 16 + fr) * 32 + fg * 8;
#pragma unroll
  for (int n = 0; n < 4; ++n) boff[n] = (wc * 64 + n * 16 + fr) * 32 + fg * 8;

  const int KLEN = NN / KSPLIT;
  const int kbeg = s * KLEN;
  const int NSTEP = KLEN / 32;

  int c0 = t, c1 = t + 256;                   // 512 16B chunks per 128x32 tile
  int r0 = c0 >> 2, kc0 = (c0 & 3) << 3;
  int r1 = c1 >> 2, kc1 = (c1 & 3) << 3;

#define SYRK_STAGE(KS, CUR)                                                   \
  {                                                                           \
    int kb = kbeg + (KS) * 32;                                                \
    int nc = kb >> 6, ko = kb & 63;                                           \
    const u16* baseA = xt + ((size_t)(b * 64 + nc) * 256 + dpA) * 64 + ko;    \
    gload16(baseA + r0 * 64 + kc0, &As[CUR][c0 * 8]);                         \
    gload16(baseA + r1 * 64 + kc1, &As[CUR][c1 * 8]);                         \
    if (!diag) {                                                              \
      const u16* baseB = xt + ((size_t)(b * 64 + nc) * 256 + dpB) * 64 + ko;  \
      gload16(baseB + r0 * 64 + kc0, &Bs[CUR][c0 * 8]);                       \
      gload16(baseB + r1 * 64 + kc1, &Bs[CUR][c1 * 8]);                       \
    }                                                                         \
  }

#define SYRK_COMPUTE(CUR)                                                     \
  {                                                                           \
    const u16* Acur = As[CUR];                                                \
    const u16* Bcur = diag ? As[CUR] : Bs[CUR];                               \
    bf16x8 af[4], bfv[4];                                                     \
    _Pragma("unroll")                                                         \
    for (int m = 0; m < 4; ++m) af[m] = *(const bf16x8*)(Acur + aoff[m]);     \
    _Pragma("unroll")                                                         \
    for (int n = 0; n < 4; ++n) bfv[n] = *(const bf16x8*)(Bcur + boff[n]);    \
    _Pragma("unroll")                                                         \
    for (int m = 0; m < 4; ++m)                                               \
      _Pragma("unroll")                                                       \
      for (int n = 0; n < 4; ++n)                                             \
        acc[m][n] = __builtin_amdgcn_mfma_f32_16x16x32_bf16(af[m], bfv[n],    \
                                                            acc[m][n], 0, 0, 0); \
  }

  // prologue
  SYRK_STAGE(0, 0);
  asm volatile("s_waitcnt vmcnt(0)" ::: "memory");
  __syncthreads();
  int cur = 0;
  for (int ks = 0; ks < NSTEP - 1; ++ks) {
    SYRK_STAGE(ks + 1, cur ^ 1);     // issue next tile's loads first
    SYRK_COMPUTE(cur);               // overlap MFMA with loads in flight
    asm volatile("s_waitcnt vmcnt(0)" ::: "memory");
    __syncthreads();
    cur ^= 1;
  }
  SYRK_COMPUTE(cur);                 // epilogue step (no prefetch)

  if (KSPLIT == 1) {
    const float* mb = mean + b * 256;
    float* ob = out + (size_t)b * NTRI;
#pragma unroll
    for (int m = 0; m < 4; ++m) {
      int i0 = ti * 128 + wr * 64 + m * 16 + fg * 4;
#pragma unroll
      for (int q = 0; q < 4; ++q) {
        int i = i0 + q;
        float mi = mb[i];
        int ro = i * 256 - ((i * (i - 1)) >> 1) - i;
#pragma unroll
        for (int n = 0; n < 4; ++n) {
          int j = tj * 128 + wc * 64 + n * 16 + fr;
          if (j >= i) ob[ro + j] = acc[m][n][q] * (1.f / 4096.f) - mi * mb[j];
        }
      }
    }
  } else {
    float* cp = covp + ((size_t)(s * 192 + t3) << 14);   // 128*128 partial
#pragma unroll
    for (int m = 0; m < 4; ++m)
#pragma unroll
      for (int q = 0; q < 4; ++q) {
        int li = wr * 64 + m * 16 + fg * 4 + q;
#pragma unroll
        for (int n = 0; n < 4; ++n) {
          int lj = wc * 64 + n * 16 + fr;
          cp[li * 128 + lj] = acc[m][n][q];
        }
      }
  }
#undef SYRK_STAGE
#undef SYRK_COMPUTE
}

// ---------- K4: mean reduce + sum K-split partials + pack triu ----------
__global__ __launch_bounds__(256) void k_fin(const float* __restrict__ covp,
                                             const float* __restrict__ part,
                                             float* __restrict__ out) {
  __shared__ float mean_s[256];
  int blk = blockIdx.x;            // b*3 + tsel
  int b = blk / 3, tsel = blk % 3;
  int ti = (tsel == 2) ? 1 : 0;
  int tj = (tsel == 0) ? 0 : 1;
  int t = threadIdx.x;

  const float* p = part + (size_t)b * 65536 + t;
  float m = 0.f;
#pragma unroll 8
  for (int q = 0; q < 256; ++q) m += p[q * 256];
  mean_s[t] = m * (1.f / 4096.f);
  __syncthreads();

  float* ob = out + (size_t)b * NTRI;
  for (int e = t; e < 16384; e += 256) {
    int li = e >> 7, lj = e & 127;
    int i = ti * 128 + li, j = tj * 128 + lj;
    if (j < i) continue;
    float ssum = 0.f;
#pragma unroll
    for (int sp = 0; sp < 4; ++sp)
      ssum += covp[((size_t)(sp * 192 + blk) << 14) + e];
    ob[i * 256 - ((i * (i - 1)) >> 1) + j - i] = ssum * (1.f / 4096.f) - mean_s[i] * mean_s[j];
  }
}

// ---------- fallback: fp32 vector SYRK, no workspace ----------
__global__ __launch_bounds__(256) void k_cov_f32(const float* __restrict__ in,
                                                 float* __restrict__ out) {
  int blk = blockIdx.x;
  int b = blk / 10, ts = blk % 10;
  int ti, tj;
  if (ts < 4)      { ti = 0; tj = ts; }
  else if (ts < 7) { ti = 1; tj = ts - 3; }
  else if (ts < 9) { ti = 2; tj = ts - 5; }
  else             { ti = 3; tj = 3; }
  bool diag = (ti == tj);

  __shared__ float Pa[32][68];
  __shared__ float Pb[32][68];
  __shared__ float smA[64], smB[64];
  int t = threadIdx.x;
  if (t < 64) { smA[t] = 0.f; smB[t] = 0.f; }
  float acc[4][4] = {};
  int ri = t >> 4, rj = t & 15;
  const float* base = in + (size_t)b * NN * ND;

  for (int ks = 0; ks < 128; ++ks) {
    int nk = ks * 32;
    __syncthreads();
    for (int cc = t; cc < 512; cc += 256) {
      int r = cc >> 4, c4 = (cc & 15) << 2;
      *(float4*)&Pa[r][c4] = *(const float4*)(base + (size_t)(nk + r) * ND + ti * 64 + c4);
      if (!diag)
        *(float4*)&Pb[r][c4] = *(const float4*)(base + (size_t)(nk + r) * ND + tj * 64 + c4);
    }
    __syncthreads();
    if (t < 64) {
      float s = 0.f;
      for (int r = 0; r < 32; ++r) s += Pa[r][t];
      smA[t] += s;
    } else if (!diag && t < 128) {
      float s = 0.f;
      for (int r = 0; r < 32; ++r) s += Pb[r][t - 64];
      smB[t - 64] += s;
    }
    float(*Pbb)[68] = diag ? Pa : Pb;
    for (int k = 0; k < 32; ++k) {
      float4 a = *(const float4*)&Pa[k][ri << 2];
      float4 v = *(const float4*)&Pbb[k][rj << 2];
      float av[4] = {a.x, a.y, a.z, a.w};
      float bv[4] = {v.x, v.y, v.z, v.w};
#pragma unroll
      for (int e = 0; e < 4; ++e)
#pragma unroll
        for (int f = 0; f < 4; ++f) acc[e][f] += av[e] * bv[f];
    }
  }
  __syncthreads();
  const float inv = 1.f / 4096.f;
  const float* mB = diag ? smA : smB;
#pragma unroll
  for (int e = 0; e < 4; ++e) {
    int i = ti * 64 + (ri << 2) + e;
    float mi = smA[(ri << 2) + e] * inv;
    int ro = i * 256 - ((i * (i - 1)) >> 1) - i;
#pragma unroll
    for (int f = 0; f < 4; ++f) {
      int j = tj * 64 + (rj << 2) + f;
      if (j >= i)
        out[(size_t)b * NTRI + ro + j] = acc[e][f] * inv - mi * mB[(rj << 2) + f] * inv;
    }
  }
}

// ---------- launch ----------
extern "C" void kernel_launch(void* const* d_in, const int* in_sizes, int n_in,
                              void* d_out, int out_size, void* d_ws, size_t ws_size,
                              hipStream_t stream) {
  const float* in = (const float*)d_in[0];
  float* out = (float*)d_out;

  const size_t XT_B   = (size_t)NB * ND * NN * 2;       // 134,217,728
  const size_t PART_B = (size_t)NB * 256 * 256 * 4;     //  16,777,216
  const size_t MEAN_B = (size_t)NB * 256 * 4;           //      65,536
  const size_t COVP_B = (size_t)4 * 192 * 16384 * 4;    //  50,331,648
  const size_t need_basic = XT_B + PART_B + MEAN_B;
  const size_t need_split = need_basic + COVP_B;

  if (ws_size >= need_basic) {
    u16*   xt   = (u16*)d_ws;
    float* part = (float*)((char*)d_ws + XT_B);
    float* mean = (float*)((char*)d_ws + XT_B + PART_B);
    k_tr<<<NB * 64, 256, 0, stream>>>(in, xt, part);
    if (ws_size >= need_split) {
      float* covp = (float*)((char*)d_ws + need_basic);
      k_syrk<4><<<NB * 3 * 4, 256, 0, stream>>>(xt, mean, out, covp);
      k_fin<<<NB * 3, 256, 0, stream>>>(covp, part, out);
    } else {
      k_mean<<<NB, 256, 0, stream>>>(part, mean);
      k_syrk<1><<<NB * 3, 256, 0, stream>>>(xt, mean, out, nullptr);
    }
  } else {
    k_cov_f32<<<NB * 10, 256, 0, stream>>>(in, out);
  }
}

// Round 4
// 85.270 us; speedup vs baseline: 2.2200x; 1.9659x over previous
//
#include <hip/hip_runtime.h>
#include <hip/hip_bf16.h>
#include <stdint.h>

typedef unsigned short u16;
typedef unsigned int   u32;

#define NB   64
#define NN   4096
#define ND   256
#define NTRI 32896   // 256*257/2
#define NSPLIT 4     // n-splits per batch
#define KROWS  1024  // rows per split
#define NCHUNK 16    // chunks per split (64 rows each)

// ---------- helpers ----------
__device__ __forceinline__ u32 cvtpk(float lo, float hi) {
  u32 r;
  asm("v_cvt_pk_bf16_f32 %0, %1, %2" : "=v"(r) : "v"(lo), "v"(hi));
  return r;
}

typedef __attribute__((ext_vector_type(8))) __bf16 bf16x8;
typedef __attribute__((ext_vector_type(4))) float  f32x4;

// ---------- fused: fp32 stream -> bf16 LDS transpose -> MFMA SYRK ----------
// grid = NB*NSPLIT = 256 blocks, 768 thr (12 waves).
// Block (b,s): streams X[b][s*1024 .. +1024][0..256) in 16 chunks of 64 rows.
// LDS tile per buffer: [ks=2][d=256][n32=32] bf16, 16B n-chunk x stored at
// x ^ ((d>>2)&3)  (write: lane owns d-quad c4 -> (d>>2)&3 = c4&3 varies;
//                  read: frag lane (fr,fg) -> j = fg ^ (fr>>2), conflict-free).
// 12 waves = 3 triu tiles x 4 quadrants of 64x64.
__global__ __launch_bounds__(768) void k_cov(const float* __restrict__ in,
                                             float* __restrict__ covp,
                                             float* __restrict__ part) {
  __shared__ alignas(16) u16 Lt[2][2][256][32];   // 64 KB (2 buffers)
  __shared__ float msum[8][256];                  // 8 KB

  int blk = blockIdx.x;
  int b = blk >> 2, s = blk & 3;
  int t = threadIdx.x;
  int w = t >> 6, lane = t & 63;

  // compute roles
  int tsel = w >> 2;               // 0:(0,0) 1:(0,1) 2:(1,1)
  int quad = w & 3;
  int wr = quad >> 1, wc = quad & 1;
  int ti = (tsel == 2) ? 1 : 0;
  int tj = (tsel == 0) ? 0 : 1;
  int fr = lane & 15, fg = lane >> 4;
  int dpA = ti * 128 + wr * 64;
  int dpB = tj * 128 + wc * 64;

  // frag byte offsets within a [256][32] plane (16 KB)
  int aoffB[4], boffB[4];
  int jj = (fg ^ (fr >> 2)) << 4;
#pragma unroll
  for (int m = 0; m < 4; ++m) aoffB[m] = (dpA + m * 16 + fr) * 64 + jj;
#pragma unroll
  for (int n = 0; n < 4; ++n) boffB[n] = (dpB + n * 16 + fr) * 64 + jj;

  // staging roles (waves 0..7)
  bool stager = (w < 8);
  int c4 = lane;                   // d-quad owned during cvt
  int ksw = w >> 2;                // which ks-plane this wave fills (0/1)
  int xw = w & 3;                  // 16B n-chunk within plane
  int swz = ((xw ^ (c4 & 3)) << 4);

  f32x4 acc[4][4];
  f32x4 zero = {0.f, 0.f, 0.f, 0.f};
#pragma unroll
  for (int m = 0; m < 4; ++m)
#pragma unroll
    for (int n = 0; n < 4; ++n) acc[m][n] = zero;

  const float4* in4 = (const float4*)(in + (size_t)b * NN * ND);
  int rbase0 = (s * KROWS + w * 8) * 64 + c4;   // float4 index of chunk-0 row0

  float4 ms = make_float4(0.f, 0.f, 0.f, 0.f);
  float4 s0, s1, s2, s3, s4, s5, s6, s7;

#define ISSUE(C)                                                \
  if (stager) {                                                 \
    int rb = rbase0 + (C) * 64 * 64;                            \
    s0 = in4[rb + 0 * 64]; s1 = in4[rb + 1 * 64];               \
    s2 = in4[rb + 2 * 64]; s3 = in4[rb + 3 * 64];               \
    s4 = in4[rb + 4 * 64]; s5 = in4[rb + 5 * 64];               \
    s6 = in4[rb + 6 * 64]; s7 = in4[rb + 7 * 64];               \
  }

#define CVT_WRITE(BUF)                                                        \
  if (stager) {                                                               \
    ms.x += s0.x + s1.x + s2.x + s3.x + s4.x + s5.x + s6.x + s7.x;            \
    ms.y += s0.y + s1.y + s2.y + s3.y + s4.y + s5.y + s6.y + s7.y;            \
    ms.z += s0.z + s1.z + s2.z + s3.z + s4.z + s5.z + s6.z + s7.z;            \
    ms.w += s0.w + s1.w + s2.w + s3.w + s4.w + s5.w + s6.w + s7.w;            \
    char* pl = (char*)&Lt[BUF][ksw][0][0];                                    \
    *(uint4*)(pl + (c4 * 4 + 0) * 64 + swz) =                                 \
      make_uint4(cvtpk(s0.x, s1.x), cvtpk(s2.x, s3.x),                        \
                 cvtpk(s4.x, s5.x), cvtpk(s6.x, s7.x));                       \
    *(uint4*)(pl + (c4 * 4 + 1) * 64 + swz) =                                 \
      make_uint4(cvtpk(s0.y, s1.y), cvtpk(s2.y, s3.y),                       \
                 cvtpk(s4.y, s5.y), cvtpk(s6.y, s7.y));                       \
    *(uint4*)(pl + (c4 * 4 + 2) * 64 + swz) =                                 \
      make_uint4(cvtpk(s0.z, s1.z), cvtpk(s2.z, s3.z),                       \
                 cvtpk(s4.z, s5.z), cvtpk(s6.z, s7.z));                       \
    *(uint4*)(pl + (c4 * 4 + 3) * 64 + swz) =                                 \
      make_uint4(cvtpk(s0.w, s1.w), cvtpk(s2.w, s3.w),                       \
                 cvtpk(s4.w, s5.w), cvtpk(s6.w, s7.w));                       \
  }

#define COMPUTE(BUF)                                                          \
  {                                                                           \
    _Pragma("unroll")                                                         \
    for (int ks = 0; ks < 2; ++ks) {                                          \
      const char* pl = (const char*)&Lt[BUF][ks][0][0];                       \
      bf16x8 af[4], bfv[4];                                                   \
      _Pragma("unroll")                                                       \
      for (int m = 0; m < 4; ++m) af[m] = *(const bf16x8*)(pl + aoffB[m]);    \
      _Pragma("unroll")                                                       \
      for (int n = 0; n < 4; ++n) bfv[n] = *(const bf16x8*)(pl + boffB[n]);   \
      _Pragma("unroll")                                                       \
      for (int m = 0; m < 4; ++m)                                             \
        _Pragma("unroll")                                                     \
        for (int n = 0; n < 4; ++n)                                           \
          acc[m][n] = __builtin_amdgcn_mfma_f32_16x16x32_bf16(                \
              af[m], bfv[n], acc[m][n], 0, 0, 0);                             \
    }                                                                         \
  }

  // 2-phase pipeline: write(c) | barrier | issue(c+1) ~ compute(c) | barrier
  ISSUE(0);
  for (int c = 0; c < NCHUNK; ++c) {
    int buf = c & 1;
    CVT_WRITE(buf);                 // compiler waits vmcnt for s0..s7 uses
    __syncthreads();
    if (c + 1 < NCHUNK) { ISSUE(c + 1); }
    COMPUTE(buf);
    __syncthreads();
  }

  // mean partials: reduce 8 staging waves' column sums -> part[(b*4+s)][256]
  if (stager) *(float4*)&msum[w][c4 * 4] = ms;
  __syncthreads();
  if (t < 256) {
    float m = 0.f;
#pragma unroll
    for (int q = 0; q < 8; ++q) m += msum[q][t];
    part[(size_t)(b * 4 + s) * 256 + t] = m;      // raw sum (k_fin divides)
  }

  // covariance partial: wave subtile -> covp[s][b*3+tsel] (128x128 tile)
  float* cp = covp + ((size_t)(s * 192 + b * 3 + tsel) << 14);
#pragma unroll
  for (int m = 0; m < 4; ++m)
#pragma unroll
    for (int q = 0; q < 4; ++q) {
      int li = wr * 64 + m * 16 + fg * 4 + q;
#pragma unroll
      for (int n = 0; n < 4; ++n) {
        int lj = wc * 64 + n * 16 + fr;
        cp[li * 128 + lj] = acc[m][n][q];
      }
    }
#undef ISSUE
#undef CVT_WRITE
#undef COMPUTE
}

// ---------- k_fin: mean reduce + sum split partials + pack triu ----------
__global__ __launch_bounds__(256) void k_fin(const float* __restrict__ covp,
                                             const float* __restrict__ part,
                                             float* __restrict__ out) {
  __shared__ float mean_s[256];
  int blk = blockIdx.x;            // b*3 + tsel
  int b = blk / 3, tsel = blk % 3;
  int ti = (tsel == 2) ? 1 : 0;
  int tj = (tsel == 0) ? 0 : 1;
  int t = threadIdx.x;

  float m = 0.f;
#pragma unroll
  for (int q = 0; q < NSPLIT; ++q) m += part[(size_t)(b * 4 + q) * 256 + t];
  mean_s[t] = m * (1.f / 4096.f);
  __syncthreads();

  float* ob = out + (size_t)b * NTRI;
  for (int e = t; e < 16384; e += 256) {
    int li = e >> 7, lj = e & 127;
    int i = ti * 128 + li, j = tj * 128 + lj;
    if (j < i) continue;
    float ssum = 0.f;
#pragma unroll
    for (int sp = 0; sp < NSPLIT; ++sp)
      ssum += covp[((size_t)(sp * 192 + blk) << 14) + e];
    ob[i * 256 - ((i * (i - 1)) >> 1) + j - i] = ssum * (1.f / 4096.f) - mean_s[i] * mean_s[j];
  }
}

// ---------- fallback: fp32 vector SYRK, no workspace ----------
__global__ __launch_bounds__(256) void k_cov_f32(const float* __restrict__ in,
                                                 float* __restrict__ out) {
  int blk = blockIdx.x;
  int b = blk / 10, ts = blk % 10;
  int ti, tj;
  if (ts < 4)      { ti = 0; tj = ts; }
  else if (ts < 7) { ti = 1; tj = ts - 3; }
  else if (ts < 9) { ti = 2; tj = ts - 5; }
  else             { ti = 3; tj = 3; }
  bool diag = (ti == tj);

  __shared__ float Pa[32][68];
  __shared__ float Pb[32][68];
  __shared__ float smA[64], smB[64];
  int t = threadIdx.x;
  if (t < 64) { smA[t] = 0.f; smB[t] = 0.f; }
  float acc[4][4] = {};
  int ri = t >> 4, rj = t & 15;
  const float* base = in + (size_t)b * NN * ND;

  for (int ks = 0; ks < 128; ++ks) {
    int nk = ks * 32;
    __syncthreads();
    for (int cc = t; cc < 512; cc += 256) {
      int r = cc >> 4, c4 = (cc & 15) << 2;
      *(float4*)&Pa[r][c4] = *(const float4*)(base + (size_t)(nk + r) * ND + ti * 64 + c4);
      if (!diag)
        *(float4*)&Pb[r][c4] = *(const float4*)(base + (size_t)(nk + r) * ND + tj * 64 + c4);
    }
    __syncthreads();
    if (t < 64) {
      float s = 0.f;
      for (int r = 0; r < 32; ++r) s += Pa[r][t];
      smA[t] += s;
    } else if (!diag && t < 128) {
      float s = 0.f;
      for (int r = 0; r < 32; ++r) s += Pb[r][t - 64];
      smB[t - 64] += s;
    }
    float(*Pbb)[68] = diag ? Pa : Pb;
    for (int k = 0; k < 32; ++k) {
      float4 a = *(const float4*)&Pa[k][ri << 2];
      float4 v = *(const float4*)&Pbb[k][rj << 2];
      float av[4] = {a.x, a.y, a.z, a.w};
      float bv[4] = {v.x, v.y, v.z, v.w};
#pragma unroll
      for (int e = 0; e < 4; ++e)
#pragma unroll
        for (int f = 0; f < 4; ++f) acc[e][f] += av[e] * bv[f];
    }
  }
  __syncthreads();
  const float inv = 1.f / 4096.f;
  const float* mB = diag ? smA : smB;
#pragma unroll
  for (int e = 0; e < 4; ++e) {
    int i = ti * 64 + (ri << 2) + e;
    float mi = smA[(ri << 2) + e] * inv;
    int ro = i * 256 - ((i * (i - 1)) >> 1) - i;
#pragma unroll
    for (int f = 0; f < 4; ++f) {
      int j = tj * 64 + (rj << 2) + f;
      if (j >= i)
        out[(size_t)b * NTRI + ro + j] = acc[e][f] * inv - mi * mB[(rj << 2) + f] * inv;
    }
  }
}

// ---------- launch ----------
extern "C" void kernel_launch(void* const* d_in, const int* in_sizes, int n_in,
                              void* d_out, int out_size, void* d_ws, size_t ws_size,
                              hipStream_t stream) {
  const float* in = (const float*)d_in[0];
  float* out = (float*)d_out;

  const size_t COVP_B = (size_t)NSPLIT * 192 * 16384 * 4;   // 50,331,648
  const size_t PART_B = (size_t)NB * NSPLIT * 256 * 4;      //     262,144
  const size_t need = COVP_B + PART_B;

  if (ws_size >= need) {
    float* covp = (float*)d_ws;
    float* part = (float*)((char*)d_ws + COVP_B);
    k_cov<<<NB * NSPLIT, 768, 0, stream>>>(in, covp, part);
    k_fin<<<NB * 3, 256, 0, stream>>>(covp, part, out);
  } else {
    k_cov_f32<<<NB * 10, 256, 0, stream>>>(in, out);
  }
}

// Round 5
// 70.303 us; speedup vs baseline: 2.6926x; 1.2129x over previous
//
#include <hip/hip_runtime.h>
#include <hip/hip_bf16.h>
#include <stdint.h>

typedef unsigned short u16;
typedef unsigned int   u32;

#define NB   64
#define NN   4096
#define ND   256
#define NTRI 32896   // 256*257/2
#define NSPLIT 4     // n-splits per batch
#define KROWS  1024  // rows per split
#define NCHUNK 16    // chunks per split (64 rows each)

// ---------- helpers ----------
__device__ __forceinline__ u32 cvtpk(float lo, float hi) {
  u32 r;
  asm("v_cvt_pk_bf16_f32 %0, %1, %2" : "=v"(r) : "v"(lo), "v"(hi));
  return r;
}

typedef __attribute__((ext_vector_type(8))) __bf16 bf16x8;
typedef __attribute__((ext_vector_type(4))) float  f32x4;

// ---------- fused: fp32 stream -> bf16 LDS transpose -> MFMA SYRK ----------
// grid = NB*NSPLIT = 256 blocks, 768 thr (12 waves).
// One barrier per chunk; loads issued 2 chunks ahead via early cvt to u-regs.
__global__ __launch_bounds__(768) void k_cov(const float* __restrict__ in,
                                             float* __restrict__ covp,
                                             float* __restrict__ part) {
  __shared__ alignas(16) u16 Lt[2][2][256][32];   // 64 KB (2 buffers)
  __shared__ float msum[8][256];                  // 8 KB

  int blk = blockIdx.x;
  int b = blk >> 2, s = blk & 3;
  int t = threadIdx.x;
  int w = t >> 6, lane = t & 63;

  // compute roles: 12 waves = 3 triu tiles x 4 quadrants of 64x64
  int tsel = w >> 2;               // 0:(0,0) 1:(0,1) 2:(1,1)
  int quad = w & 3;
  int wr = quad >> 1, wc = quad & 1;
  int ti = (tsel == 2) ? 1 : 0;
  int tj = (tsel == 0) ? 0 : 1;
  bool diag = (ti == tj);
  bool alive = !(diag && quad == 2);   // (1,0) quadrant of diag tile: redundant
  int fr = lane & 15, fg = lane >> 4;
  int dpA = ti * 128 + wr * 64;
  int dpB = tj * 128 + wc * 64;

  // frag byte offsets within a [256][32] plane (16 KB)
  int aoffB[4], boffB[4];
  int jj = (fg ^ (fr >> 2)) << 4;
#pragma unroll
  for (int m = 0; m < 4; ++m) aoffB[m] = (dpA + m * 16 + fr) * 64 + jj;
#pragma unroll
  for (int n = 0; n < 4; ++n) boffB[n] = (dpB + n * 16 + fr) * 64 + jj;

  // staging roles (waves 0..7): wave w covers n_local rows w*8..w*8+7
  bool stager = (w < 8);
  int c4 = lane;                   // d-quad owned during cvt (rows d=4*c4+e)
  int ksw = w >> 2;                // ks-plane this wave fills (0/1)
  int xw = w & 3;                  // 16B n-chunk within plane
  int swz = ((xw ^ (c4 & 3)) << 4);

  f32x4 acc[4][4];
  f32x4 zero = {0.f, 0.f, 0.f, 0.f};
#pragma unroll
  for (int m = 0; m < 4; ++m)
#pragma unroll
    for (int n = 0; n < 4; ++n) acc[m][n] = zero;

  const float4* in4 = (const float4*)(in + (size_t)b * NN * ND);
  int rbase0 = (s * KROWS + w * 8) * 64 + c4;   // float4 index of chunk-0 row0

  float4 ms = make_float4(0.f, 0.f, 0.f, 0.f);
  float4 s0, s1, s2, s3, s4, s5, s6, s7;        // fp32 staging (1 set)
  uint4 q0, q1, q2, q3;                         // converted bf16 (1 set)

#define ISSUE(C)                                                \
  if (stager && (C) < NCHUNK) {                                 \
    int rb = rbase0 + (C) * 4096;                               \
    s0 = in4[rb + 0 * 64]; s1 = in4[rb + 1 * 64];               \
    s2 = in4[rb + 2 * 64]; s3 = in4[rb + 3 * 64];               \
    s4 = in4[rb + 4 * 64]; s5 = in4[rb + 5 * 64];               \
    s6 = in4[rb + 6 * 64]; s7 = in4[rb + 7 * 64];               \
  }

#define CVT()                                                                 \
  if (stager) {                                                               \
    ms.x += s0.x + s1.x + s2.x + s3.x + s4.x + s5.x + s6.x + s7.x;            \
    ms.y += s0.y + s1.y + s2.y + s3.y + s4.y + s5.y + s6.y + s7.y;            \
    ms.z += s0.z + s1.z + s2.z + s3.z + s4.z + s5.z + s6.z + s7.z;            \
    ms.w += s0.w + s1.w + s2.w + s3.w + s4.w + s5.w + s6.w + s7.w;            \
    q0 = make_uint4(cvtpk(s0.x, s1.x), cvtpk(s2.x, s3.x),                     \
                    cvtpk(s4.x, s5.x), cvtpk(s6.x, s7.x));                    \
    q1 = make_uint4(cvtpk(s0.y, s1.y), cvtpk(s2.y, s3.y),                     \
                    cvtpk(s4.y, s5.y), cvtpk(s6.y, s7.y));                    \
    q2 = make_uint4(cvtpk(s0.z, s1.z), cvtpk(s2.z, s3.z),                     \
                    cvtpk(s4.z, s5.z), cvtpk(s6.z, s7.z));                    \
    q3 = make_uint4(cvtpk(s0.w, s1.w), cvtpk(s2.w, s3.w),                     \
                    cvtpk(s4.w, s5.w), cvtpk(s6.w, s7.w));                    \
  }

#define WRITE(BUF)                                                            \
  if (stager) {                                                               \
    char* pl = (char*)&Lt[BUF][ksw][0][0] + swz;                              \
    *(uint4*)(pl + (c4 * 4 + 0) * 64) = q0;                                   \
    *(uint4*)(pl + (c4 * 4 + 1) * 64) = q1;                                   \
    *(uint4*)(pl + (c4 * 4 + 2) * 64) = q2;                                   \
    *(uint4*)(pl + (c4 * 4 + 3) * 64) = q3;                                   \
  }

#define COMPUTE(BUF)                                                          \
  if (alive) {                                                                \
    _Pragma("unroll")                                                         \
    for (int ks = 0; ks < 2; ++ks) {                                          \
      const char* pl = (const char*)&Lt[BUF][ks][0][0];                       \
      bf16x8 af[4], bfv[4];                                                   \
      _Pragma("unroll")                                                       \
      for (int m = 0; m < 4; ++m) af[m] = *(const bf16x8*)(pl + aoffB[m]);    \
      _Pragma("unroll")                                                       \
      for (int n = 0; n < 4; ++n) bfv[n] = *(const bf16x8*)(pl + boffB[n]);   \
      _Pragma("unroll")                                                       \
      for (int m = 0; m < 4; ++m)                                             \
        _Pragma("unroll")                                                     \
        for (int n = 0; n < 4; ++n)                                           \
          acc[m][n] = __builtin_amdgcn_mfma_f32_16x16x32_bf16(                \
              af[m], bfv[n], acc[m][n], 0, 0, 0);                             \
    }                                                                         \
  }

  // prologue: stage chunk 0, issue chunk 1
  ISSUE(0);
  CVT();
  ISSUE(1);
  WRITE(0);
  __syncthreads();
  // steady state: one barrier per chunk; loads 2 ahead
  for (int c = 0; c < NCHUNK - 1; ++c) {
    CVT();                      // chunk c+1 (waits counted vmcnt; c+2 not yet issued)
    ISSUE(c + 2);               // refill fp32 set (WAR-ordered after CVT reads)
    WRITE((c + 1) & 1);         // buf[(c+1)&1]: prev reader COMPUTE was before last bar
    COMPUTE(c & 1);
    __syncthreads();
  }
  COMPUTE((NCHUNK - 1) & 1);    // final chunk

  // mean partials: reduce 8 staging waves' column sums -> part[(b*4+s)][256]
  if (stager) *(float4*)&msum[w][c4 * 4] = ms;
  __syncthreads();
  if (t < 256) {
    float m = 0.f;
#pragma unroll
    for (int q = 0; q < 8; ++q) m += msum[q][t];
    part[(size_t)(b * 4 + s) * 256 + t] = m;      // raw sum (k_fin divides)
  }

  // covariance partial: wave subtile -> covp[s][b*3+tsel] (128x128 tile)
  if (alive) {
    float* cp = covp + ((size_t)(s * 192 + b * 3 + tsel) << 14);
#pragma unroll
    for (int m = 0; m < 4; ++m)
#pragma unroll
      for (int q = 0; q < 4; ++q) {
        int li = wr * 64 + m * 16 + fg * 4 + q;
#pragma unroll
        for (int n = 0; n < 4; ++n) {
          int lj = wc * 64 + n * 16 + fr;
          cp[li * 128 + lj] = acc[m][n][q];
        }
      }
  }
#undef ISSUE
#undef CVT
#undef WRITE
#undef COMPUTE
}

// ---------- k_fin: mean reduce + sum split partials + pack triu ----------
// grid = 64*3*2 = 384 blocks; each handles half a 128x128 tile, float4 reads.
__global__ __launch_bounds__(256) void k_fin(const float* __restrict__ covp,
                                             const float* __restrict__ part,
                                             float* __restrict__ out) {
  __shared__ float mean_s[256];
  int blk = blockIdx.x;
  int tile = blk >> 1, half = blk & 1;   // tile = b*3 + tsel
  int b = tile / 3, tsel = tile % 3;
  int ti = (tsel == 2) ? 1 : 0;
  int tj = (tsel == 0) ? 0 : 1;
  int t = threadIdx.x;

  float m = 0.f;
#pragma unroll
  for (int q = 0; q < NSPLIT; ++q) m += part[(size_t)(b * 4 + q) * 256 + t];
  mean_s[t] = m * (1.f / 4096.f);
  __syncthreads();

  const float4* cp0 = (const float4*)(covp + ((size_t)(0 * 192 + tile) << 14));
  const float4* cp1 = (const float4*)(covp + ((size_t)(1 * 192 + tile) << 14));
  const float4* cp2 = (const float4*)(covp + ((size_t)(2 * 192 + tile) << 14));
  const float4* cp3 = (const float4*)(covp + ((size_t)(3 * 192 + tile) << 14));

  float* ob = out + (size_t)b * NTRI;
  for (int e4 = t; e4 < 2048; e4 += 256) {
    int e = half * 8192 + (e4 << 2);
    int li = e >> 7, lj0 = e & 127;      // 4 consecutive lj in same row
    int i = ti * 128 + li;
    if (tj * 128 + lj0 + 3 < i) continue;   // whole quad below diagonal
    int q = e >> 2;
    float4 v0 = cp0[q], v1 = cp1[q], v2 = cp2[q], v3 = cp3[q];
    float sum[4] = {v0.x + v1.x + v2.x + v3.x, v0.y + v1.y + v2.y + v3.y,
                    v0.z + v1.z + v2.z + v3.z, v0.w + v1.w + v2.w + v3.w};
    float mi = mean_s[i];
    int ro = i * 256 - ((i * (i - 1)) >> 1) - i;
#pragma unroll
    for (int k = 0; k < 4; ++k) {
      int j = tj * 128 + lj0 + k;
      if (j >= i)
        ob[ro + j] = sum[k] * (1.f / 4096.f) - mi * mean_s[j];
    }
  }
}

// ---------- fallback: fp32 vector SYRK, no workspace ----------
__global__ __launch_bounds__(256) void k_cov_f32(const float* __restrict__ in,
                                                 float* __restrict__ out) {
  int blk = blockIdx.x;
  int b = blk / 10, ts = blk % 10;
  int ti, tj;
  if (ts < 4)      { ti = 0; tj = ts; }
  else if (ts < 7) { ti = 1; tj = ts - 3; }
  else if (ts < 9) { ti = 2; tj = ts - 5; }
  else             { ti = 3; tj = 3; }
  bool diag = (ti == tj);

  __shared__ float Pa[32][68];
  __shared__ float Pb[32][68];
  __shared__ float smA[64], smB[64];
  int t = threadIdx.x;
  if (t < 64) { smA[t] = 0.f; smB[t] = 0.f; }
  float acc[4][4] = {};
  int ri = t >> 4, rj = t & 15;
  const float* base = in + (size_t)b * NN * ND;

  for (int ks = 0; ks < 128; ++ks) {
    int nk = ks * 32;
    __syncthreads();
    for (int cc = t; cc < 512; cc += 256) {
      int r = cc >> 4, c4 = (cc & 15) << 2;
      *(float4*)&Pa[r][c4] = *(const float4*)(base + (size_t)(nk + r) * ND + ti * 64 + c4);
      if (!diag)
        *(float4*)&Pb[r][c4] = *(const float4*)(base + (size_t)(nk + r) * ND + tj * 64 + c4);
    }
    __syncthreads();
    if (t < 64) {
      float s = 0.f;
      for (int r = 0; r < 32; ++r) s += Pa[r][t];
      smA[t] += s;
    } else if (!diag && t < 128) {
      float s = 0.f;
      for (int r = 0; r < 32; ++r) s += Pb[r][t - 64];
      smB[t - 64] += s;
    }
    float(*Pbb)[68] = diag ? Pa : Pb;
    for (int k = 0; k < 32; ++k) {
      float4 a = *(const float4*)&Pa[k][ri << 2];
      float4 v = *(const float4*)&Pbb[k][rj << 2];
      float av[4] = {a.x, a.y, a.z, a.w};
      float bv[4] = {v.x, v.y, v.z, v.w};
#pragma unroll
      for (int e = 0; e < 4; ++e)
#pragma unroll
        for (int f = 0; f < 4; ++f) acc[e][f] += av[e] * bv[f];
    }
  }
  __syncthreads();
  const float inv = 1.f / 4096.f;
  const float* mB = diag ? smA : smB;
#pragma unroll
  for (int e = 0; e < 4; ++e) {
    int i = ti * 64 + (ri << 2) + e;
    float mi = smA[(ri << 2) + e] * inv;
    int ro = i * 256 - ((i * (i - 1)) >> 1) - i;
#pragma unroll
    for (int f = 0; f < 4; ++f) {
      int j = tj * 64 + (rj << 2) + f;
      if (j >= i)
        out[(size_t)b * NTRI + ro + j] = acc[e][f] * inv - mi * mB[(rj << 2) + f] * inv;
    }
  }
}

// ---------- launch ----------
extern "C" void kernel_launch(void* const* d_in, const int* in_sizes, int n_in,
                              void* d_out, int out_size, void* d_ws, size_t ws_size,
                              hipStream_t stream) {
  const float* in = (const float*)d_in[0];
  float* out = (float*)d_out;

  const size_t COVP_B = (size_t)NSPLIT * 192 * 16384 * 4;   // 50,331,648
  const size_t PART_B = (size_t)NB * NSPLIT * 256 * 4;      //     262,144
  const size_t need = COVP_B + PART_B;

  if (ws_size >= need) {
    float* covp = (float*)d_ws;
    float* part = (float*)((char*)d_ws + COVP_B);
    k_cov<<<NB * NSPLIT, 768, 0, stream>>>(in, covp, part);
    k_fin<<<NB * 3 * 2, 256, 0, stream>>>(covp, part, out);
  } else {
    k_cov_f32<<<NB * 10, 256, 0, stream>>>(in, out);
  }
}